// Round 1
// baseline (522.879 us; speedup 1.0000x reference)
//
#include <hip/hip_runtime.h>

#define RR 32
#define R3 32768
#define BATCH 8
#define CH 64
#define NPTS 100000
#define NPOINTS (BATCH * NPTS)   // 800000
#define NVOX (BATCH * R3)        // 262144

typedef unsigned int uint32;
typedef unsigned short uint16;

// ---------------------------------------------------------------------------
// Phase 1: voxel id per point (u16 local id) + global histogram + coords out.
// ---------------------------------------------------------------------------
__global__ __launch_bounds__(256) void phase1_count(
    const float* __restrict__ coords,  // [B, 3, N]
    uint16* __restrict__ vox,          // [NPOINTS] local voxel id (0..32767)
    uint32* __restrict__ cnt,          // [NVOX] (pre-zeroed)
    float* __restrict__ out2)          // [B, 3, N] voxel coords as float
{
    int gid = blockIdx.x * blockDim.x + threadIdx.x;
    if (gid >= NPOINTS) return;
    int b = gid / NPTS;
    int n = gid - b * NPTS;

    const float* cb = coords + (size_t)b * 3 * NPTS + n;
    float fx = fminf(fmaxf(cb[0]        * 32.0f, 0.0f), 31.0f);
    float fy = fminf(fmaxf(cb[NPTS]     * 32.0f, 0.0f), 31.0f);
    float fz = fminf(fmaxf(cb[2 * NPTS] * 32.0f, 0.0f), 31.0f);
    int x = (int)rintf(fx);   // round-half-even matches jnp.round
    int y = (int)rintf(fy);
    int z = (int)rintf(fz);
    int v = x * (RR * RR) + y * RR + z;

    float* o2 = out2 + (size_t)b * 3 * NPTS + n;
    o2[0]        = (float)x;
    o2[NPTS]     = (float)y;
    o2[2 * NPTS] = (float)z;

    vox[gid] = (uint16)v;
    atomicAdd(&cnt[b * R3 + v], 1u);
}

// ---------------------------------------------------------------------------
// Fused accumulate+average: one block per (batch, channel).
// LDS fp32 accumulator covers the full R^3 grid (128 KiB).
// feat reads are coalesced float4 streams; the only scattered op is
// ds_add_f32 (no-return LDS atomic, fire-and-forget).
// ---------------------------------------------------------------------------
__global__ __launch_bounds__(1024) void accum_lds(
    const float* __restrict__ feat,    // [B, C, N]
    const uint16* __restrict__ vox,    // [B*N] local voxel ids
    const uint32* __restrict__ cnt,    // [NVOX]
    float* __restrict__ out1)          // [B, C, R3]
{
    extern __shared__ float acc[];     // [R3] = 131072 B
    int b = blockIdx.x >> 6;
    int c = blockIdx.x & 63;
    int tid = threadIdx.x;

    // zero the accumulator: 32768 floats = 8192 float4, 1024 threads x 8
    float4* a4 = (float4*)acc;
#pragma unroll
    for (int i = 0; i < 8; ++i)
        a4[i * 1024 + tid] = make_float4(0.f, 0.f, 0.f, 0.f);
    __syncthreads();

    // stream this (b,c) feature row + voxel ids; accumulate into LDS
    const float4*  f4 = (const float4*)(feat + ((size_t)b * CH + c) * NPTS);
    const ushort4* v4 = (const ushort4*)(vox + (size_t)b * NPTS);
    const int NQ = NPTS / 4;           // 25000, NPTS % 4 == 0
    for (int i = 0; i < 25; ++i) {
        int idx = i * 1024 + tid;
        if (idx < NQ) {
            float4  f = f4[idx];
            ushort4 v = v4[idx];
            atomicAdd(&acc[v.x], f.x);
            atomicAdd(&acc[v.y], f.y);
            atomicAdd(&acc[v.z], f.z);
            atomicAdd(&acc[v.w], f.w);
        }
    }
    __syncthreads();

    // finalize: divide by count, coalesced float4 write
    const uint4* c4 = (const uint4*)(cnt + (size_t)b * R3);
    float4*      o4 = (float4*)(out1 + ((size_t)b * CH + c) * R3);
#pragma unroll
    for (int i = 0; i < 8; ++i) {
        int idx = i * 1024 + tid;
        uint4  cc = c4[idx];
        float4 s  = a4[idx];
        float4 r;
        r.x = s.x / (float)(cc.x > 1u ? cc.x : 1u);
        r.y = s.y / (float)(cc.y > 1u ? cc.y : 1u);
        r.z = s.z / (float)(cc.z > 1u ? cc.z : 1u);
        r.w = s.w / (float)(cc.w > 1u ? cc.w : 1u);
        o4[idx] = r;
    }
}

// ---------------------------------------------------------------------------
// Fallback (tiny ws): direct atomic accumulate into d_out.
// ---------------------------------------------------------------------------
__global__ __launch_bounds__(256) void accum_direct(
    const float* __restrict__ feat, const float* __restrict__ coords,
    float* __restrict__ out1, uint32* __restrict__ cnt, float* __restrict__ out2)
{
    int gid = blockIdx.x * blockDim.x + threadIdx.x;
    if (gid >= NPOINTS) return;
    int b = gid / NPTS;
    int n = gid - b * NPTS;
    const float* cb = coords + (size_t)b * 3 * NPTS + n;
    float fx = fminf(fmaxf(cb[0]        * 32.0f, 0.0f), 31.0f);
    float fy = fminf(fmaxf(cb[NPTS]     * 32.0f, 0.0f), 31.0f);
    float fz = fminf(fmaxf(cb[2 * NPTS] * 32.0f, 0.0f), 31.0f);
    int x = (int)rintf(fx), y = (int)rintf(fy), z = (int)rintf(fz);
    int v = x * (RR * RR) + y * RR + z;
    float* o2 = out2 + (size_t)b * 3 * NPTS + n;
    o2[0] = (float)x; o2[NPTS] = (float)y; o2[2 * NPTS] = (float)z;
    atomicAdd(&cnt[b * R3 + v], 1u);
    float* obase = out1 + (size_t)(b * CH) * R3 + v;
    const float* frow = feat + (size_t)(b * CH) * NPTS + n;
#pragma unroll 8
    for (int c = 0; c < CH; ++c)
        unsafeAtomicAdd(&obase[(size_t)c * R3], frow[(size_t)c * NPTS]);
}

__global__ __launch_bounds__(256) void finalize_direct(
    float* __restrict__ out1, const uint32* __restrict__ cnt)
{
    size_t gid = (size_t)blockIdx.x * blockDim.x + threadIdx.x;
    size_t total = (size_t)BATCH * CH * R3;
    if (gid >= total) return;
    int v = (int)(gid & (R3 - 1));
    int b = (int)(gid / ((size_t)CH * R3));
    uint32 ct = cnt[b * R3 + v];
    out1[gid] = out1[gid] / (float)(ct > 1u ? ct : 1u);
}

// ---------------------------------------------------------------------------
extern "C" void kernel_launch(void* const* d_in, const int* in_sizes, int n_in,
                              void* d_out, int out_size, void* d_ws, size_t ws_size,
                              hipStream_t stream)
{
    const float* feat   = (const float*)d_in[0];   // [8, 64, 100000]
    const float* coords = (const float*)d_in[1];   // [8, 3, 100000]

    float* out1 = (float*)d_out;                          // [8, 64, 32768]
    float* out2 = out1 + (size_t)BATCH * CH * R3;         // [8, 3, 100000]

    // ws layout
    const size_t vox_off   = 0;
    const size_t vox_bytes = (size_t)NPOINTS * 2;                  // 1.6 MB
    const size_t cnt_off   = (vox_off + vox_bytes + 255) & ~255ull;
    const size_t cnt_bytes = (size_t)NVOX * 4;                     // 1 MB
    const size_t need      = cnt_off + cnt_bytes;

    const int npt_blocks = (NPOINTS + 255) / 256;   // 3125

    if (ws_size >= need) {
        char* ws = (char*)d_ws;
        uint16* vox = (uint16*)(ws + vox_off);
        uint32* cnt = (uint32*)(ws + cnt_off);

        hipMemsetAsync(cnt, 0, cnt_bytes, stream);
        phase1_count<<<npt_blocks, 256, 0, stream>>>(coords, vox, cnt, out2);
        // 512 blocks = (batch, channel) pairs, 128 KiB dynamic LDS each
        accum_lds<<<BATCH * CH, 1024, R3 * sizeof(float), stream>>>(feat, vox, cnt, out1);
    } else {
        // fallback: direct atomic accumulate into d_out
        uint32* cnt = (uint32*)d_ws;
        hipMemsetAsync(out1, 0, (size_t)BATCH * CH * R3 * sizeof(float), stream);
        hipMemsetAsync(d_ws, 0, (size_t)NVOX * 4, stream);
        accum_direct<<<npt_blocks, 256, 0, stream>>>(feat, coords, out1, cnt, out2);
        size_t total = (size_t)BATCH * CH * R3;
        finalize_direct<<<(unsigned)((total + 255) / 256), 256, 0, stream>>>(out1, cnt);
    }
}